// Round 3
// baseline (332.921 us; speedup 1.0000x reference)
//
#include <hip/hip_runtime.h>

// ---------------------------------------------------------------------------
// Discriminator fused pipeline for MI355X (gfx950)
//
// Math identities:
//   h1[b, i*64+r, o] = relu( A1[b*64+r, o] + sum_t W1b_red[o][t]*x_bi[r*8+t] + b1[o] )
//     where A1 = input_flat @ W1a^T,  W1b_red[o][t] = sum_{u<64} gmlp1_w[o][512+t*64+u],
//           x_bi = input[b, i, :]
//   layers 2,3: transposed MFMA GEMMs D[o][m], weights as A-operand (global/L2),
//   activations as B-operand in LDS with XOR-swizzled chunk layout:
//     elem (row r, col c) lives at r*512 + (((c>>3) ^ (r&7))<<3) + (c&7)
//   -> exactly 64 KB LDS, 8-lanes-per-4-bank-group (conflict-free min) on b128.
//
// Head shapes (round-2 fix): d1_w is (512,1024), d2_w is (2,512) — hidden=512.
// ---------------------------------------------------------------------------

typedef float f32x4 __attribute__((ext_vector_type(4)));
typedef __bf16 bf16x8v __attribute__((ext_vector_type(8)));
typedef __bf16 bf16x4v __attribute__((ext_vector_type(4)));

// workspace byte offsets
#define WS_A1      0u           // 1024*512 f32      = 2 MB
#define WS_W1BR    2097152u     // 512*8 f32         = 16 KB
#define WS_SENT    2113536u     // 16*512 f32        = 32 KB
#define WS_Y       2146304u     // 16*512 f32        = 32 KB
#define WS_IMGEMB  2179072u     // 16*512 f32        = 32 KB
#define WS_W2BF    2211840u     // 512*512 bf16      = 512 KB
#define WS_W3BF    2736128u     // 512*512 bf16      = 512 KB
// total ~3.26 MB

// ---------------------------------------------------------------------------
// Prep kernel: A1 GEMM (blocks 0..127), W2/W3 bf16 convert (128..383),
// W1b_red (384..399), im-linear y = im_input @ im_w^T + im_b (400..911)
// ---------------------------------------------------------------------------
__global__ __launch_bounds__(256) void k_prep(
    const float* __restrict__ input, const float* __restrict__ im_input,
    const float* __restrict__ g1w, const float* __restrict__ g2w,
    const float* __restrict__ g3w, const float* __restrict__ imw,
    const float* __restrict__ imb, float* __restrict__ ws)
{
  __shared__ float As[16][72];
  __shared__ float Bs[16][72];
  const int blk = blockIdx.x, t = threadIdx.x;
  float* A1   = ws;
  float* w1br = (float*)((char*)ws + WS_W1BR);
  float* yv   = (float*)((char*)ws + WS_Y);
  __bf16* w2bf = (__bf16*)((char*)ws + WS_W2BF);
  __bf16* w3bf = (__bf16*)((char*)ws + WS_W3BF);

  if (blk < 128) {
    // A1[1024,512] = input_flat[1024,512] @ W1a^T ; W1a = gmlp1_w[:, :512]
    const int tm = blk >> 3, tn = blk & 7;
    const int m0 = tm * 64, o0 = tn * 64;
    const int ty = t >> 4, tx = t & 15;
    const int lrow = t >> 2, lk4 = (t & 3) * 4;
    float acc[4][4] = {};
    for (int kc = 0; kc < 512; kc += 16) {
      float4 av = *(const float4*)(input + (m0 + lrow) * 512 + kc + lk4);
      float4 bw = *(const float4*)(g1w + (size_t)(o0 + lrow) * 1024 + kc + lk4);
      __syncthreads();
      As[lk4 + 0][lrow] = av.x; As[lk4 + 1][lrow] = av.y;
      As[lk4 + 2][lrow] = av.z; As[lk4 + 3][lrow] = av.w;
      Bs[lk4 + 0][lrow] = bw.x; Bs[lk4 + 1][lrow] = bw.y;
      Bs[lk4 + 2][lrow] = bw.z; Bs[lk4 + 3][lrow] = bw.w;
      __syncthreads();
#pragma unroll
      for (int kk = 0; kk < 16; ++kk) {
        float a4[4], b4[4];
        *(float4*)a4 = *(const float4*)&As[kk][4 * ty];
        *(float4*)b4 = *(const float4*)&Bs[kk][4 * tx];
#pragma unroll
        for (int ii = 0; ii < 4; ++ii)
#pragma unroll
          for (int jj = 0; jj < 4; ++jj)
            acc[ii][jj] += a4[ii] * b4[jj];
      }
    }
#pragma unroll
    for (int ii = 0; ii < 4; ++ii) {
      float4 o;
      o.x = acc[ii][0]; o.y = acc[ii][1]; o.z = acc[ii][2]; o.w = acc[ii][3];
      *(float4*)(A1 + (m0 + 4 * ty + ii) * 512 + o0 + 4 * tx) = o;
    }
  } else if (blk < 384) {
    // convert gmlp2_w / gmlp3_w to bf16 (row-major [out][in])
    int idx = ((blk - 128) * 256 + t) * 8;
    const float* src; __bf16* dst; int off;
    if (idx < 262144) { src = g2w; dst = w2bf; off = idx; }
    else              { src = g3w; dst = w3bf; off = idx - 262144; }
    float4 v0 = *(const float4*)(src + off);
    float4 v1 = *(const float4*)(src + off + 4);
    bf16x8v h;
    h[0] = (__bf16)v0.x; h[1] = (__bf16)v0.y; h[2] = (__bf16)v0.z; h[3] = (__bf16)v0.w;
    h[4] = (__bf16)v1.x; h[5] = (__bf16)v1.y; h[6] = (__bf16)v1.z; h[7] = (__bf16)v1.w;
    *(bf16x8v*)(dst + off) = h;
  } else if (blk < 400) {
    // W1b_red[o][s] = sum_{u<64} gmlp1_w[o][512 + s*64 + u]
    int idx = (blk - 384) * 256 + t;      // 0..4095
    int o = idx >> 3, s = idx & 7;
    const float* p = g1w + (size_t)o * 1024 + 512 + s * 64;
    float sum = 0.f;
#pragma unroll
    for (int u = 0; u < 64; u += 4) {
      float4 v = *(const float4*)(p + u);
      sum += v.x + v.y + v.z + v.w;
    }
    w1br[o * 8 + s] = sum;
  } else {
    // y[b][o] = dot(im_input[b], im_w[o]) + im_b[o]; one block per o
    int o = blk - 400;                    // 0..511
    int wv = t >> 6, l = t & 63;
    const float* wrow = imw + (size_t)o * 2048;
    for (int bb = 0; bb < 4; ++bb) {
      int b = wv * 4 + bb;
      const float* xr = im_input + (size_t)b * 2048;
      float s = 0.f;
#pragma unroll
      for (int u = 0; u < 8; ++u) {
        int k = u * 256 + l * 4;
        float4 xv = *(const float4*)(xr + k);
        float4 wx = *(const float4*)(wrow + k);
        s += xv.x * wx.x + xv.y * wx.y + xv.z * wx.z + xv.w * wx.w;
      }
#pragma unroll
      for (int m = 32; m >= 1; m >>= 1) s += __shfl_xor(s, m);
      if (l == 0) yv[b * 512 + o] = s + imb[o];
    }
  }
}

// ---------------------------------------------------------------------------
// Transposed-GEMM K-loop: D[o'][m] += W[o'][k] * h[m][k]
//   A-frag: W[o'=base+16*ot+p16][k = ks*32 + quad*8 + j]      (global, L2-hot)
//   B-frag: h[m = p16+16*mt][k = ks*32 + quad*8 + j]          (LDS, swizzled)
//   D: lane l, reg r -> D[o' = 16*ot + quad*4 + r][m = 16*mt + p16]
// ---------------------------------------------------------------------------
__device__ __forceinline__ void kloop(const __bf16* __restrict__ wp,
                                      const __bf16* __restrict__ hbuf,
                                      int p16, int quad, f32x4 acc[8][4])
{
  const int msk = p16 & 7;
#pragma unroll 2
  for (int ks = 0; ks < 16; ++ks) {
    const int kc = ks * 4 + quad;          // k-chunk index (8 elems)
    bf16x8v bf[4];
#pragma unroll
    for (int mt = 0; mt < 4; ++mt) {
      const int m = p16 + 16 * mt;
      bf[mt] = *(const bf16x8v*)(hbuf + m * 512 + ((kc ^ msk) << 3));
    }
#pragma unroll
    for (int ot = 0; ot < 8; ++ot) {
      bf16x8v af = *(const bf16x8v*)(wp + ot * 16 * 512 + ks * 32);
#pragma unroll
      for (int mt = 0; mt < 4; ++mt)
        acc[ot][mt] = __builtin_amdgcn_mfma_f32_16x16x32_bf16(af, bf[mt], acc[ot][mt], 0, 0, 0);
    }
  }
}

// ---------------------------------------------------------------------------
// Main fused kernel: blocks 0..1023 = (b,i) pair tiles; block 1024 = BatchNorm
// ---------------------------------------------------------------------------
__global__ __launch_bounds__(256, 2) void k_main(
    const float* __restrict__ input,
    const float* __restrict__ g1b, const float* __restrict__ g2b,
    const float* __restrict__ g3b,
    const float* __restrict__ bng, const float* __restrict__ bnb,
    float* __restrict__ ws)
{
  const int blk = blockIdx.x, t = threadIdx.x;
  float* A1   = ws;
  float* w1br = (float*)((char*)ws + WS_W1BR);
  float* sent = (float*)((char*)ws + WS_SENT);
  float* yv   = (float*)((char*)ws + WS_Y);
  float* imge = (float*)((char*)ws + WS_IMGEMB);
  const __bf16* w2bf = (const __bf16*)((char*)ws + WS_W2BF);
  const __bf16* w3bf = (const __bf16*)((char*)ws + WS_W3BF);

  if (blk == 1024) {
    // BatchNorm1d (training-mode batch stats) + ReLU over y[16][512]
#pragma unroll
    for (int rep = 0; rep < 2; ++rep) {
      int o = t + rep * 256;
      float vals[16];
      float mu = 0.f;
#pragma unroll
      for (int b = 0; b < 16; ++b) { vals[b] = yv[b * 512 + o]; mu += vals[b]; }
      mu *= (1.f / 16.f);
      float var = 0.f;
#pragma unroll
      for (int b = 0; b < 16; ++b) { float d = vals[b] - mu; var += d * d; }
      var *= (1.f / 16.f);
      float sc = bng[o] * rsqrtf(var + 1e-5f);
      float sh = bnb[o] - mu * sc;
#pragma unroll
      for (int b = 0; b < 16; ++b)
        imge[b * 512 + o] = fmaxf(vals[b] * sc + sh, 0.f);
    }
    return;
  }

  // exactly 64 KB static LDS (per-workgroup limit-safe)
  __shared__ __align__(16) __bf16 hbuf[32768];   // 64 rows x 512 cols, swizzled

  const int b = blk >> 6, i = blk & 63;
  const int w = t >> 6, l = t & 63;

  // x row (input[b,i,:]) distributed in registers: lane l holds x[l*8 .. l*8+7]
  float xreg[8];
  {
    const float* xr = input + (size_t)(b * 64 + i) * 512 + l * 8;
    *(float4*)xreg       = *(const float4*)xr;
    *(float4*)(xreg + 4) = *(const float4*)(xr + 4);
  }

  // ---- phase 1: h1 -> LDS (bf16, swizzled) ----
  {
    const int oc = l, rg = w;             // oc: output-chunk 0..63, rg: wave id
    float wreg[64];
    const float4* wp4 = (const float4*)(w1br + oc * 64);
#pragma unroll
    for (int q = 0; q < 16; ++q) ((float4*)wreg)[q] = wp4[q];
    float bv[8];
    *(float4*)bv       = *(const float4*)(g1b + oc * 8);
    *(float4*)(bv + 4) = *(const float4*)(g1b + oc * 8 + 4);
    for (int j = 0; j < 16; ++j) {
      int r = j * 4 + rg;                 // wave-uniform row
      const float* ap = A1 + (size_t)(b * 64 + r) * 512 + oc * 8;
      float av[8];
      *(float4*)av       = *(const float4*)ap;
      *(float4*)(av + 4) = *(const float4*)(ap + 4);
      float xr[8];
#pragma unroll
      for (int p = 0; p < 8; ++p) xr[p] = __shfl(xreg[p], r);  // readlane bcast
      bf16x8v hv;
#pragma unroll
      for (int q = 0; q < 8; ++q) {
        float s = av[q] + bv[q];
#pragma unroll
        for (int p = 0; p < 8; ++p) s += wreg[q * 8 + p] * xr[p];
        hv[q] = (__bf16)fmaxf(s, 0.f);
      }
      *(bf16x8v*)(hbuf + r * 512 + ((oc ^ (r & 7)) << 3)) = hv;
    }
  }
  __syncthreads();

  const int quad = l >> 4, p16 = l & 15;

  // ---- phase 2: h2 = relu(h1 @ W2^T + b2), transposed MFMA ----
  f32x4 acc[8][4];
#pragma unroll
  for (int ot = 0; ot < 8; ++ot)
#pragma unroll
    for (int mt = 0; mt < 4; ++mt) { f32x4 z = {0.f, 0.f, 0.f, 0.f}; acc[ot][mt] = z; }

  kloop(w2bf + (size_t)(w * 128 + p16) * 512 + quad * 8, hbuf, p16, quad, acc);
  __syncthreads();  // all h1 reads done before overwrite
#pragma unroll
  for (int ot = 0; ot < 8; ++ot) {
    float4 b2 = *(const float4*)(g2b + w * 128 + ot * 16 + quad * 4);
#pragma unroll
    for (int mt = 0; mt < 4; ++mt) {
      f32x4 v = acc[ot][mt];
      bf16x4v h;
      h[0] = (__bf16)fmaxf(v[0] + b2.x, 0.f);
      h[1] = (__bf16)fmaxf(v[1] + b2.y, 0.f);
      h[2] = (__bf16)fmaxf(v[2] + b2.z, 0.f);
      h[3] = (__bf16)fmaxf(v[3] + b2.w, 0.f);
      int row = p16 + 16 * mt;
      int col = w * 128 + ot * 16 + quad * 4;
      *(bf16x4v*)(hbuf + row * 512 + (((col >> 3) ^ (row & 7)) << 3) + (col & 7)) = h;
    }
  }
  __syncthreads();

  // ---- phase 3: h3 = relu(h2 @ W3^T + b3), fused mean-reduce ----
#pragma unroll
  for (int ot = 0; ot < 8; ++ot)
#pragma unroll
    for (int mt = 0; mt < 4; ++mt) { f32x4 z = {0.f, 0.f, 0.f, 0.f}; acc[ot][mt] = z; }

  kloop(w3bf + (size_t)(w * 128 + p16) * 512 + quad * 8, hbuf, p16, quad, acc);

#pragma unroll
  for (int ot = 0; ot < 8; ++ot) {
    float4 b3 = *(const float4*)(g3b + w * 128 + ot * 16 + quad * 4);
    float bb[4] = {b3.x, b3.y, b3.z, b3.w};
#pragma unroll
    for (int r = 0; r < 4; ++r) {
      float s = 0.f;
#pragma unroll
      for (int mt = 0; mt < 4; ++mt) s += fmaxf(acc[ot][mt][r] + bb[r], 0.f);
      s += __shfl_xor(s, 1);
      s += __shfl_xor(s, 2);
      s += __shfl_xor(s, 4);
      s += __shfl_xor(s, 8);
      if (p16 == 0)
        atomicAdd(&sent[b * 512 + w * 128 + ot * 16 + quad * 4 + r], s * (1.0f / 4096.0f));
    }
  }
}

// ---------------------------------------------------------------------------
// Head: emb = [sent, img_emb] (16x1024); h = relu(emb @ d1^T + b1)  (16x512);
// out = h @ d2^T + b2  (16x2).  d1_w: (512,1024), d2_w: (2,512).
// One block per b, 512 threads: thread t computes hidden row t.
// ---------------------------------------------------------------------------
__global__ __launch_bounds__(512) void k_head(
    const float* __restrict__ d1w, const float* __restrict__ d1b,
    const float* __restrict__ d2w, const float* __restrict__ d2b,
    const float* __restrict__ ws, float* __restrict__ out)
{
  __shared__ float emb[1024];
  __shared__ float red0[512];
  __shared__ float red1[512];
  const float* sent = (const float*)((const char*)ws + WS_SENT);
  const float* imge = (const float*)((const char*)ws + WS_IMGEMB);
  const int b = blockIdx.x, t = threadIdx.x;   // t in [0,512)
  emb[t]       = sent[b * 512 + t];
  emb[512 + t] = imge[b * 512 + t];
  __syncthreads();
  // hidden row t: h = relu(d1b[t] + dot(d1w[t, 0:1024], emb))
  const float* wr = d1w + (size_t)t * 1024;
  float s = d1b[t];
  for (int k = 0; k < 1024; k += 4) {
    float4 wv = *(const float4*)(wr + k);
    float4 ev = *(const float4*)(emb + k);
    s += wv.x * ev.x + wv.y * ev.y + wv.z * ev.z + wv.w * ev.w;
  }
  float h = fmaxf(s, 0.f);
  // out row: p0 = sum_k d2w[0][k] h[k], p1 = sum_k d2w[1][k] h[k]
  red0[t] = d2w[t] * h;
  red1[t] = d2w[512 + t] * h;
  __syncthreads();
  for (int s2 = 256; s2 > 0; s2 >>= 1) {
    if (t < s2) { red0[t] += red0[t + s2]; red1[t] += red1[t + s2]; }
    __syncthreads();
  }
  if (t == 0) {
    out[b * 2 + 0] = red0[0] + d2b[0];
    out[b * 2 + 1] = red1[0] + d2b[1];
  }
}

// ---------------------------------------------------------------------------
extern "C" void kernel_launch(void* const* d_in, const int* in_sizes, int n_in,
                              void* d_out, int out_size, void* d_ws, size_t ws_size,
                              hipStream_t stream)
{
  const float* input    = (const float*)d_in[0];
  const float* im_input = (const float*)d_in[1];
  const float* g1w = (const float*)d_in[2];
  const float* g1b = (const float*)d_in[3];
  const float* g2w = (const float*)d_in[4];
  const float* g2b = (const float*)d_in[5];
  const float* g3w = (const float*)d_in[6];
  const float* g3b = (const float*)d_in[7];
  const float* imw = (const float*)d_in[8];
  const float* imb = (const float*)d_in[9];
  const float* bng = (const float*)d_in[10];
  const float* bnb = (const float*)d_in[11];
  const float* d1w = (const float*)d_in[12];
  const float* d1b = (const float*)d_in[13];
  const float* d2w = (const float*)d_in[14];
  const float* d2b = (const float*)d_in[15];
  float* out = (float*)d_out;
  float* ws  = (float*)d_ws;

  hipMemsetAsync((char*)d_ws + WS_SENT, 0, 16 * 512 * 4, stream);
  k_prep<<<912, 256, 0, stream>>>(input, im_input, g1w, g2w, g3w, imw, imb, ws);
  k_main<<<1025, 256, 0, stream>>>(input, g1b, g2b, g3b, bng, bnb, ws);
  k_head<<<16, 512, 0, stream>>>(d1w, d1b, d2w, d2b, ws, out);
}

// Round 4
// 234.868 us; speedup vs baseline: 1.4175x; 1.4175x over previous
//
#include <hip/hip_runtime.h>

// ---------------------------------------------------------------------------
// Discriminator fused pipeline for MI355X (gfx950)
//
// Math identities:
//   h1[b, i*64+r, o] = relu( A1[b*64+r, o] + sum_t W1b_red[o][t]*x_bi[r*8+t] + b1[o] )
//     where A1 = input_flat @ W1a^T,  W1b_red[o][t] = sum_{u<64} gmlp1_w[o][512+t*64+u]
//   layers 2,3: transposed MFMA GEMMs D[o][m], weights as A-operand streamed from
//   L2 in a PRE-SWIZZLED lane-contiguous layout (1 KB/wave/instr), activations as
//   B-operand in LDS with XOR-swizzled chunk layout:
//     elem (row r, col c) at r*512 + (((c>>3) ^ (r&7))<<3) + (c&7)   (64 KB LDS)
//
// Weight swizzle (per 512x512 layer): elem (o,k) stored at
//   (o>>4)*8192 + (k>>5)*512 + ( ((k>>3)&3)*16 + (o&15) )*8 + (k&7)
// so lane l = quad*16+p16 reads W[obase+16*ot+p16][ks*32+quad*8+j] at
//   base + (w*8+ot)*8192 + ks*512 + l*8   -> fully coalesced.
// ---------------------------------------------------------------------------

typedef float f32x4 __attribute__((ext_vector_type(4)));
typedef __bf16 bf16x8v __attribute__((ext_vector_type(8)));
typedef __bf16 bf16x4v __attribute__((ext_vector_type(4)));

// workspace byte offsets
#define WS_A1      0u           // 1024*512 f32      = 2 MB
#define WS_W1BR    2097152u     // 512*8 f32         = 16 KB
#define WS_SENT    2113536u     // 16*512 f32        = 32 KB
#define WS_Y       2146304u     // 16*512 f32 (im-linear y, then head hidden h)
#define WS_IMGEMB  2179072u     // 16*512 f32        = 32 KB
#define WS_W2BF    2211840u     // 512*512 bf16      = 512 KB (swizzled)
#define WS_W3BF    2736128u     // 512*512 bf16      = 512 KB (swizzled)
// total ~3.11 MB

// ---------------------------------------------------------------------------
// Prep kernel: A1 GEMM (blocks 0..127), W2/W3 bf16 swizzled convert (128..383),
// W1b_red (384..399), im-linear y = im_input @ im_w^T + im_b (400..911)
// ---------------------------------------------------------------------------
__global__ __launch_bounds__(256) void k_prep(
    const float* __restrict__ input, const float* __restrict__ im_input,
    const float* __restrict__ g1w, const float* __restrict__ g2w,
    const float* __restrict__ g3w, const float* __restrict__ imw,
    const float* __restrict__ imb, float* __restrict__ ws)
{
  __shared__ float As[16][72];
  __shared__ float Bs[16][72];
  const int blk = blockIdx.x, t = threadIdx.x;
  float* A1   = ws;
  float* w1br = (float*)((char*)ws + WS_W1BR);
  float* yv   = (float*)((char*)ws + WS_Y);
  __bf16* w2bf = (__bf16*)((char*)ws + WS_W2BF);
  __bf16* w3bf = (__bf16*)((char*)ws + WS_W3BF);

  if (blk < 128) {
    // A1[1024,512] = input_flat[1024,512] @ W1a^T ; W1a = gmlp1_w[:, :512]
    const int tm = blk >> 3, tn = blk & 7;
    const int m0 = tm * 64, o0 = tn * 64;
    const int ty = t >> 4, tx = t & 15;
    const int lrow = t >> 2, lk4 = (t & 3) * 4;
    float acc[4][4] = {};
    for (int kc = 0; kc < 512; kc += 16) {
      float4 av = *(const float4*)(input + (m0 + lrow) * 512 + kc + lk4);
      float4 bw = *(const float4*)(g1w + (size_t)(o0 + lrow) * 1024 + kc + lk4);
      __syncthreads();
      As[lk4 + 0][lrow] = av.x; As[lk4 + 1][lrow] = av.y;
      As[lk4 + 2][lrow] = av.z; As[lk4 + 3][lrow] = av.w;
      Bs[lk4 + 0][lrow] = bw.x; Bs[lk4 + 1][lrow] = bw.y;
      Bs[lk4 + 2][lrow] = bw.z; Bs[lk4 + 3][lrow] = bw.w;
      __syncthreads();
#pragma unroll
      for (int kk = 0; kk < 16; ++kk) {
        float a4[4], b4[4];
        *(float4*)a4 = *(const float4*)&As[kk][4 * ty];
        *(float4*)b4 = *(const float4*)&Bs[kk][4 * tx];
#pragma unroll
        for (int ii = 0; ii < 4; ++ii)
#pragma unroll
          for (int jj = 0; jj < 4; ++jj)
            acc[ii][jj] += a4[ii] * b4[jj];
      }
    }
#pragma unroll
    for (int ii = 0; ii < 4; ++ii) {
      float4 o;
      o.x = acc[ii][0]; o.y = acc[ii][1]; o.z = acc[ii][2]; o.w = acc[ii][3];
      *(float4*)(A1 + (m0 + 4 * ty + ii) * 512 + o0 + 4 * tx) = o;
    }
  } else if (blk < 384) {
    // convert gmlp2_w / gmlp3_w to bf16 in MFMA A-frag swizzled layout
    int idx = ((blk - 128) * 256 + t) * 8;
    const float* src; __bf16* dst; int off;
    if (idx < 262144) { src = g2w; dst = w2bf; off = idx; }
    else              { src = g3w; dst = w3bf; off = idx - 262144; }
    int o = off >> 9, k = off & 511;
    int ks = k >> 5, quad = (k >> 3) & 3;
    int doff = (o >> 4) * 8192 + ks * 512 + (quad * 16 + (o & 15)) * 8;
    float4 v0 = *(const float4*)(src + off);
    float4 v1 = *(const float4*)(src + off + 4);
    bf16x8v h;
    h[0] = (__bf16)v0.x; h[1] = (__bf16)v0.y; h[2] = (__bf16)v0.z; h[3] = (__bf16)v0.w;
    h[4] = (__bf16)v1.x; h[5] = (__bf16)v1.y; h[6] = (__bf16)v1.z; h[7] = (__bf16)v1.w;
    *(bf16x8v*)(dst + doff) = h;
  } else if (blk < 400) {
    // W1b_red[o][s] = sum_{u<64} gmlp1_w[o][512 + s*64 + u]
    int idx = (blk - 384) * 256 + t;      // 0..4095
    int o = idx >> 3, s = idx & 7;
    const float* p = g1w + (size_t)o * 1024 + 512 + s * 64;
    float sum = 0.f;
#pragma unroll
    for (int u = 0; u < 64; u += 4) {
      float4 v = *(const float4*)(p + u);
      sum += v.x + v.y + v.z + v.w;
    }
    w1br[o * 8 + s] = sum;
  } else {
    // y[b][o] = dot(im_input[b], im_w[o]) + im_b[o]; one block per o
    int o = blk - 400;                    // 0..511
    int wv = t >> 6, l = t & 63;
    const float* wrow = imw + (size_t)o * 2048;
    for (int bb = 0; bb < 4; ++bb) {
      int b = wv * 4 + bb;
      const float* xr = im_input + (size_t)b * 2048;
      float s = 0.f;
#pragma unroll
      for (int u = 0; u < 8; ++u) {
        int k = u * 256 + l * 4;
        float4 xv = *(const float4*)(xr + k);
        float4 wx = *(const float4*)(wrow + k);
        s += xv.x * wx.x + xv.y * wx.y + xv.z * wx.z + xv.w * wx.w;
      }
#pragma unroll
      for (int m = 32; m >= 1; m >>= 1) s += __shfl_xor(s, m);
      if (l == 0) yv[b * 512 + o] = s + imb[o];
    }
  }
}

// ---------------------------------------------------------------------------
// Transposed-GEMM K-loop with explicit A-frag register double-buffer.
//   wl = layer base + (w*8)*8192 + l*8   (swizzled layout, 1KB/wave/load)
//   B-frag from swizzled LDS; D: lane l, reg r -> D[16*ot+quad*4+r][16*mt+p16]
// ---------------------------------------------------------------------------
__device__ __forceinline__ void kloop(const __bf16* __restrict__ wl,
                                      const __bf16* __restrict__ hbuf,
                                      int p16, int quad, f32x4 acc[8][4])
{
  const int msk3 = (p16 & 7) << 3;
  bf16x8v a0[4], a1[4], an[4];
#pragma unroll
  for (int ot = 0; ot < 4; ++ot) a0[ot] = *(const bf16x8v*)(wl + ot * 8192);
#pragma unroll
  for (int ot = 0; ot < 4; ++ot) a1[ot] = *(const bf16x8v*)(wl + (ot + 4) * 8192);
#pragma unroll 2
  for (int ks = 0; ks < 16; ++ks) {
    // LDS B-frags for this ks (issued together; latency amortized over MFMAs)
    const int kcb = (((ks * 4 + quad) << 3) ^ msk3);
    bf16x8v bf[4];
#pragma unroll
    for (int mt = 0; mt < 4; ++mt)
      bf[mt] = *(const bf16x8v*)(hbuf + (p16 + 16 * mt) * 512 + kcb);
    // prefetch first half of next ks A-frags (a full MFMA-iter ahead)
    if (ks < 15) {
#pragma unroll
      for (int ot = 0; ot < 4; ++ot)
        an[ot] = *(const bf16x8v*)(wl + (ks + 1) * 512 + ot * 8192);
    }
#pragma unroll
    for (int ot = 0; ot < 4; ++ot)
#pragma unroll
      for (int mt = 0; mt < 4; ++mt)
        acc[ot][mt] = __builtin_amdgcn_mfma_f32_16x16x32_bf16(a0[ot], bf[mt], acc[ot][mt], 0, 0, 0);
#pragma unroll
    for (int ot = 0; ot < 4; ++ot)
#pragma unroll
      for (int mt = 0; mt < 4; ++mt)
        acc[4 + ot][mt] = __builtin_amdgcn_mfma_f32_16x16x32_bf16(a1[ot], bf[mt], acc[4 + ot][mt], 0, 0, 0);
    if (ks < 15) {
#pragma unroll
      for (int ot = 0; ot < 4; ++ot)
        a1[ot] = *(const bf16x8v*)(wl + (ks + 1) * 512 + (ot + 4) * 8192);
#pragma unroll
      for (int ot = 0; ot < 4; ++ot) a0[ot] = an[ot];
    }
  }
}

// ---------------------------------------------------------------------------
// Main fused kernel: blocks 0..1023 = (b,i) pair tiles; block 1024 = BatchNorm
// ---------------------------------------------------------------------------
__global__ __launch_bounds__(256, 2) void k_main(
    const float* __restrict__ input,
    const float* __restrict__ g1b, const float* __restrict__ g2b,
    const float* __restrict__ g3b,
    const float* __restrict__ bng, const float* __restrict__ bnb,
    float* __restrict__ ws)
{
  const int blk = blockIdx.x, t = threadIdx.x;
  float* A1   = ws;
  float* w1br = (float*)((char*)ws + WS_W1BR);
  float* sent = (float*)((char*)ws + WS_SENT);
  float* yv   = (float*)((char*)ws + WS_Y);
  float* imge = (float*)((char*)ws + WS_IMGEMB);
  const __bf16* w2bf = (const __bf16*)((char*)ws + WS_W2BF);
  const __bf16* w3bf = (const __bf16*)((char*)ws + WS_W3BF);

  if (blk == 1024) {
    // BatchNorm1d (training-mode batch stats) + ReLU over y[16][512]
#pragma unroll
    for (int rep = 0; rep < 2; ++rep) {
      int o = t + rep * 256;
      float vals[16];
      float mu = 0.f;
#pragma unroll
      for (int b = 0; b < 16; ++b) { vals[b] = yv[b * 512 + o]; mu += vals[b]; }
      mu *= (1.f / 16.f);
      float var = 0.f;
#pragma unroll
      for (int b = 0; b < 16; ++b) { float d = vals[b] - mu; var += d * d; }
      var *= (1.f / 16.f);
      float sc = bng[o] * rsqrtf(var + 1e-5f);
      float sh = bnb[o] - mu * sc;
#pragma unroll
      for (int b = 0; b < 16; ++b)
        imge[b * 512 + o] = fmaxf(vals[b] * sc + sh, 0.f);
    }
    return;
  }

  // exactly 64 KB static LDS
  __shared__ __align__(16) __bf16 hbuf[32768];   // 64 rows x 512 cols, swizzled

  const int b = blk >> 6, i = blk & 63;
  const int w = t >> 6, l = t & 63;

  // x row (input[b,i,:]) distributed in registers: lane l holds x[l*8 .. l*8+7]
  float xreg[8];
  {
    const float* xr = input + (size_t)(b * 64 + i) * 512 + l * 8;
    *(float4*)xreg       = *(const float4*)xr;
    *(float4*)(xreg + 4) = *(const float4*)(xr + 4);
  }

  // ---- phase 1: h1 -> LDS (bf16, swizzled) ----
  {
    const int oc = l, rg = w;             // oc: output-chunk 0..63, rg: wave id
    float wreg[64];
    const float4* wp4 = (const float4*)(w1br + oc * 64);
#pragma unroll
    for (int q = 0; q < 16; ++q) ((float4*)wreg)[q] = wp4[q];
    float bv[8];
    *(float4*)bv       = *(const float4*)(g1b + oc * 8);
    *(float4*)(bv + 4) = *(const float4*)(g1b + oc * 8 + 4);
#pragma unroll 4
    for (int j = 0; j < 16; ++j) {
      int r = j * 4 + rg;                 // wave-uniform row
      const float* ap = A1 + (size_t)(b * 64 + r) * 512 + oc * 8;
      float av[8];
      *(float4*)av       = *(const float4*)ap;
      *(float4*)(av + 4) = *(const float4*)(ap + 4);
      float xr[8];
#pragma unroll
      for (int p = 0; p < 8; ++p) xr[p] = __shfl(xreg[p], r);  // readlane bcast
      bf16x8v hv;
#pragma unroll
      for (int q = 0; q < 8; ++q) {
        float s = av[q] + bv[q];
#pragma unroll
        for (int p = 0; p < 8; ++p) s += wreg[q * 8 + p] * xr[p];
        hv[q] = (__bf16)fmaxf(s, 0.f);
      }
      *(bf16x8v*)(hbuf + r * 512 + ((oc ^ (r & 7)) << 3)) = hv;
    }
  }
  __syncthreads();

  const int quad = l >> 4, p16 = l & 15;

  // ---- phase 2: h2 = relu(h1 @ W2^T + b2), transposed MFMA ----
  f32x4 acc[8][4];
#pragma unroll
  for (int ot = 0; ot < 8; ++ot)
#pragma unroll
    for (int mt = 0; mt < 4; ++mt) { f32x4 z = {0.f, 0.f, 0.f, 0.f}; acc[ot][mt] = z; }

  kloop(w2bf + (size_t)(w * 8) * 8192 + l * 8, hbuf, p16, quad, acc);
  __syncthreads();  // all h1 reads done before overwrite
#pragma unroll
  for (int ot = 0; ot < 8; ++ot) {
    float4 b2 = *(const float4*)(g2b + w * 128 + ot * 16 + quad * 4);
#pragma unroll
    for (int mt = 0; mt < 4; ++mt) {
      f32x4 v = acc[ot][mt];
      bf16x4v h;
      h[0] = (__bf16)fmaxf(v[0] + b2.x, 0.f);
      h[1] = (__bf16)fmaxf(v[1] + b2.y, 0.f);
      h[2] = (__bf16)fmaxf(v[2] + b2.z, 0.f);
      h[3] = (__bf16)fmaxf(v[3] + b2.w, 0.f);
      int row = p16 + 16 * mt;
      int col = w * 128 + ot * 16 + quad * 4;
      *(bf16x4v*)(hbuf + row * 512 + (((col >> 3) ^ (row & 7)) << 3) + (col & 7)) = h;
    }
  }
  __syncthreads();

  // ---- phase 3: h3 = relu(h2 @ W3^T + b3), fused mean-reduce ----
#pragma unroll
  for (int ot = 0; ot < 8; ++ot)
#pragma unroll
    for (int mt = 0; mt < 4; ++mt) { f32x4 z = {0.f, 0.f, 0.f, 0.f}; acc[ot][mt] = z; }

  kloop(w3bf + (size_t)(w * 8) * 8192 + l * 8, hbuf, p16, quad, acc);

#pragma unroll
  for (int ot = 0; ot < 8; ++ot) {
    float4 b3 = *(const float4*)(g3b + w * 128 + ot * 16 + quad * 4);
    float bb[4] = {b3.x, b3.y, b3.z, b3.w};
#pragma unroll
    for (int r = 0; r < 4; ++r) {
      float s = 0.f;
#pragma unroll
      for (int mt = 0; mt < 4; ++mt) s += fmaxf(acc[ot][mt][r] + bb[r], 0.f);
      s += __shfl_xor(s, 1);
      s += __shfl_xor(s, 2);
      s += __shfl_xor(s, 4);
      s += __shfl_xor(s, 8);
      if (p16 == 0)
        atomicAdd(&sent[b * 512 + w * 128 + ot * 16 + quad * 4 + r], s * (1.0f / 4096.0f));
    }
  }
}

// ---------------------------------------------------------------------------
// Head stage 1: h[b][row] = relu(d1b[row] + dot(d1w[row], [sent_b, imge_b]))
// 64 blocks = 16 b x 4 row-slices of 128; h -> WS_Y (y is dead after BN).
// ---------------------------------------------------------------------------
__global__ __launch_bounds__(128) void k_head1(
    const float* __restrict__ d1w, const float* __restrict__ d1b,
    const float* __restrict__ ws_in, float* __restrict__ hout)
{
  __shared__ float emb[1024];
  const float* sent = (const float*)((const char*)ws_in + WS_SENT);
  const float* imge = (const float*)((const char*)ws_in + WS_IMGEMB);
  const int b = blockIdx.x >> 2, sl = blockIdx.x & 3, t = threadIdx.x;
#pragma unroll
  for (int q = 0; q < 4; ++q) emb[t * 4 + q] = sent[b * 512 + t * 4 + q];
#pragma unroll
  for (int q = 0; q < 4; ++q) emb[512 + t * 4 + q] = imge[b * 512 + t * 4 + q];
  __syncthreads();
  const int row = sl * 128 + t;
  const float* wr = d1w + (size_t)row * 1024;
  float s = d1b[row];
  for (int k = 0; k < 1024; k += 4) {
    float4 wv = *(const float4*)(wr + k);
    float4 ev = *(const float4*)(emb + k);
    s += wv.x * ev.x + wv.y * ev.y + wv.z * ev.z + wv.w * ev.w;
  }
  hout[b * 512 + row] = fmaxf(s, 0.f);
}

// ---------------------------------------------------------------------------
// Head stage 2: out[b] = h[b] @ d2^T + d2b   (d2_w: (2,512))
// ---------------------------------------------------------------------------
__global__ __launch_bounds__(512) void k_head2(
    const float* __restrict__ d2w, const float* __restrict__ d2b,
    const float* __restrict__ hin, float* __restrict__ out)
{
  __shared__ float red0[512];
  __shared__ float red1[512];
  const int b = blockIdx.x, t = threadIdx.x;
  float h = hin[b * 512 + t];
  red0[t] = d2w[t] * h;
  red1[t] = d2w[512 + t] * h;
  __syncthreads();
  for (int s2 = 256; s2 > 0; s2 >>= 1) {
    if (t < s2) { red0[t] += red0[t + s2]; red1[t] += red1[t + s2]; }
    __syncthreads();
  }
  if (t == 0) {
    out[b * 2 + 0] = red0[0] + d2b[0];
    out[b * 2 + 1] = red1[0] + d2b[1];
  }
}

// ---------------------------------------------------------------------------
extern "C" void kernel_launch(void* const* d_in, const int* in_sizes, int n_in,
                              void* d_out, int out_size, void* d_ws, size_t ws_size,
                              hipStream_t stream)
{
  const float* input    = (const float*)d_in[0];
  const float* im_input = (const float*)d_in[1];
  const float* g1w = (const float*)d_in[2];
  const float* g1b = (const float*)d_in[3];
  const float* g2w = (const float*)d_in[4];
  const float* g2b = (const float*)d_in[5];
  const float* g3w = (const float*)d_in[6];
  const float* g3b = (const float*)d_in[7];
  const float* imw = (const float*)d_in[8];
  const float* imb = (const float*)d_in[9];
  const float* bng = (const float*)d_in[10];
  const float* bnb = (const float*)d_in[11];
  const float* d1w = (const float*)d_in[12];
  const float* d1b = (const float*)d_in[13];
  const float* d2w = (const float*)d_in[14];
  const float* d2b = (const float*)d_in[15];
  float* out = (float*)d_out;
  float* ws  = (float*)d_ws;

  hipMemsetAsync((char*)d_ws + WS_SENT, 0, 16 * 512 * 4, stream);
  k_prep<<<912, 256, 0, stream>>>(input, im_input, g1w, g2w, g3w, imw, imb, ws);
  k_main<<<1025, 256, 0, stream>>>(input, g1b, g2b, g3b, bng, bnb, ws);
  k_head1<<<64, 128, 0, stream>>>(d1w, d1b, ws, (float*)((char*)d_ws + WS_Y));
  k_head2<<<16, 512, 0, stream>>>(d2w, d2b, (const float*)((char*)d_ws + WS_Y), out);
}